// Round 1
// baseline (804.676 us; speedup 1.0000x reference)
//
#include <hip/hip_runtime.h>
#include <cstdint>
#include <cstddef>

// Problem: D_OUT=32768, D_IN=1024, all fp32 inputs.
// total = sum(DW*Z) + lamb_reg*sum(1-(2Th-1)^2) + 0.05*4*sum_i (sum_j W*Z)^2
// where DW = W - s*(Q+Th), Z = DW @ Sigma^T  (Z[i,j] = sum_k DW[i,k]*Sigma[j,k])

#define DOUT 32768
#define DIN  1024

typedef __bf16 bf16x8 __attribute__((ext_vector_type(8)));
typedef float  f32x4  __attribute__((ext_vector_type(4)));

__device__ __forceinline__ unsigned short f2bf(float f) {
  union { float f; unsigned u; } v; v.f = f;
  unsigned u = v.u + 0x7fffu + ((v.u >> 16) & 1u);   // RNE
  return (unsigned short)(u >> 16);
}
__device__ __forceinline__ float bf2f(unsigned short b) {
  union { float f; unsigned u; } v; v.u = ((unsigned)b) << 16;
  return v.f;
}

// ---------------- Pass 1: DW = W - s*(Q+Th) in bf16, + binary_reg ----------------
__global__ __launch_bounds__(256) void prep(
    const float4* __restrict__ W4, const float4* __restrict__ Q4,
    const float4* __restrict__ T4, const float* __restrict__ s,
    ushort4* __restrict__ DW4, float* __restrict__ acc)
{
  const int row = blockIdx.x;          // one row (1024 el = 256 float4) per block
  const int tid = threadIdx.x;
  const size_t idx = (size_t)row * 256 + tid;
  const float sv = s[row];
  const float4 wv = W4[idx];
  const float4 qv = Q4[idx];
  const float4 tv = T4[idx];
  float bsum = 0.f;
  ushort4 dp;
#define COMP(fld) { \
    float th = 0.6f * tanhf(tv.fld) + 0.5f; \
    th = fminf(fmaxf(th, 0.f), 1.f); \
    float um = 2.f * th - 1.f; \
    bsum += 1.f - um * um; \
    dp.fld = f2bf(wv.fld - sv * (qv.fld + th)); }
  COMP(x) COMP(y) COMP(z) COMP(w)
#undef COMP
  DW4[idx] = dp;

  for (int off = 32; off; off >>= 1) bsum += __shfl_down(bsum, off);
  __shared__ float r4[4];
  if ((tid & 63) == 0) r4[tid >> 6] = bsum;
  __syncthreads();
  if (tid == 0) atomicAdd(acc, 2.0e-4f * (r4[0] + r4[1] + r4[2] + r4[3]));
}

// ---------------- Sigma fp32 -> bf16 ----------------
__global__ __launch_bounds__(256) void sconv(const float4* __restrict__ S4,
                                             ushort4* __restrict__ O4)
{
  const int idx = blockIdx.x * 256 + threadIdx.x;
  float4 v = S4[idx];
  ushort4 o;
  o.x = f2bf(v.x); o.y = f2bf(v.y); o.z = f2bf(v.z); o.w = f2bf(v.w);
  O4[idx] = o;
}

// ---------------- Fused GEMM: Z = DW @ Sigma^T, epilogue reduces ----------------
// 128x128 tile, BK=64, 256 thr (4 waves, 2x2 wave grid, 64x64 each, 4x4 mfma 16x16x32)
__global__ __launch_bounds__(256, 2) void gemm_fused(
    const unsigned short* __restrict__ DW,   // [DOUT][DIN] bf16 bits
    const unsigned short* __restrict__ SG,   // [DIN][DIN]  bf16 bits (Sigma row-major = B^T layout)
    const float* __restrict__ Wf,            // [DOUT][DIN] fp32
    float* __restrict__ t_arr,               // [DOUT]
    float* __restrict__ acc)                 // scalar accumulator
{
  constexpr int K = DIN;
  const int n0 = blockIdx.x * 128;   // 8 n-blocks (fast: same-m neighbors for L2/L3 reuse)
  const int m0 = blockIdx.y * 128;   // 256 m-blocks
  const int tid = threadIdx.x;
  const int w = tid >> 6;
  const int lane = tid & 63;
  const int wr = w >> 1, wc = w & 1;

  __shared__ unsigned short As[128 * 64];    // [row][k] 128B pitch
  __shared__ unsigned short Bs[128 * 64];
  __shared__ float red4[4];

  f32x4 accr[4][4];
#pragma unroll
  for (int i = 0; i < 4; ++i)
#pragma unroll
    for (int j = 0; j < 4; ++j) accr[i][j] = (f32x4){0.f, 0.f, 0.f, 0.f};

  const int l8 = lane >> 3;           // sub-row within 1KB chunk
  const int lc = (lane & 7) << 3;     // k-element offset (8 bf16 = 16B)

  for (int kt = 0; kt < K / 64; ++kt) {
    const int k0 = kt * 64;
#pragma unroll
    for (int c = 0; c < 4; ++c) {
      const int sub  = c * 4 + w;               // 0..15 : which 1KB LDS chunk
      const int rowa = sub * 8 + l8;            // 0..127 tile row
      const int ldso = (sub * 64 + lane) * 8;   // element offset (lane*16B within chunk)
      const unsigned short* ga = DW + (size_t)(m0 + rowa) * K + (k0 + lc);
      const unsigned short* gb = SG + (size_t)(n0 + rowa) * K + (k0 + lc);
      __builtin_amdgcn_global_load_lds(
          (const __attribute__((address_space(1))) void*)ga,
          (__attribute__((address_space(3))) void*)(As + ldso), 16, 0, 0);
      __builtin_amdgcn_global_load_lds(
          (const __attribute__((address_space(1))) void*)gb,
          (__attribute__((address_space(3))) void*)(Bs + ldso), 16, 0, 0);
    }
    __syncthreads();   // compiler emits vmcnt(0) drain before barrier

    {
      const int q  = lane >> 4;
      const int mr = lane & 15;
#pragma unroll
      for (int kk = 0; kk < 64; kk += 32) {
        bf16x8 af[4], bfr[4];
        const int kf = kk + q * 8;
#pragma unroll
        for (int ti = 0; ti < 4; ++ti)
          af[ti] = *(const bf16x8*)&As[(wr * 64 + ti * 16 + mr) * 64 + kf];
#pragma unroll
        for (int tj = 0; tj < 4; ++tj)
          bfr[tj] = *(const bf16x8*)&Bs[(wc * 64 + tj * 16 + mr) * 64 + kf];
#pragma unroll
        for (int ti = 0; ti < 4; ++ti)
#pragma unroll
          for (int tj = 0; tj < 4; ++tj)
            accr[ti][tj] = __builtin_amdgcn_mfma_f32_16x16x32_bf16(
                af[ti], bfr[tj], accr[ti][tj], 0, 0, 0);
      }
    }
    __syncthreads();
  }

  // Epilogue: C/D layout col=lane&15, row=(lane>>4)*4+reg
  const int q  = lane >> 4;
  const int cn = lane & 15;
  float actp = 0.f;
#pragma unroll
  for (int ti = 0; ti < 4; ++ti) {
#pragma unroll
    for (int r = 0; r < 4; ++r) {
      const int i = m0 + wr * 64 + ti * 16 + q * 4 + r;
      const float*          wrow  = Wf + (size_t)i * K;
      const unsigned short* dwrow = DW + (size_t)i * K;
      float ts = 0.f;
#pragma unroll
      for (int tj = 0; tj < 4; ++tj) {
        const int j = n0 + wc * 64 + tj * 16 + cn;
        const float z = accr[ti][tj][r];
        ts   = fmaf(wrow[j], z, ts);          // t_i partial
        actp = fmaf(bf2f(dwrow[j]), z, actp); // activation partial
      }
      // reduce across the 16 lanes sharing this row (cols differ)
#pragma unroll
      for (int off = 8; off; off >>= 1) ts += __shfl_xor(ts, off, 16);
      if (cn == 0) atomicAdd(&t_arr[i], ts);
    }
  }
  for (int off = 32; off; off >>= 1) actp += __shfl_down(actp, off);
  if (lane == 0) red4[w] = actp;
  __syncthreads();
  if (tid == 0) atomicAdd(acc, red4[0] + red4[1] + red4[2] + red4[3]);
}

// ---------------- Final: out = acc + 0.2 * sum(t_i^2) ----------------
__global__ __launch_bounds__(1024) void finish(const float* __restrict__ t_arr,
                                               const float* __restrict__ acc,
                                               float* __restrict__ out)
{
  __shared__ float red[16];
  float g = 0.f;
  for (int i = threadIdx.x; i < DOUT; i += 1024) {
    float t = t_arr[i];
    g = fmaf(t, t, g);
  }
  for (int off = 32; off; off >>= 1) g += __shfl_down(g, off);
  if ((threadIdx.x & 63) == 0) red[threadIdx.x >> 6] = g;
  __syncthreads();
  if (threadIdx.x == 0) {
    float tot = 0.f;
#pragma unroll
    for (int i = 0; i < 16; ++i) tot += red[i];
    out[0] = acc[0] + 0.2f * tot;   // lamb * 4 = 0.05*4 = 0.2
  }
}

extern "C" void kernel_launch(void* const* d_in, const int* in_sizes, int n_in,
                              void* d_out, int out_size, void* d_ws, size_t ws_size,
                              hipStream_t stream) {
  const float* W     = (const float*)d_in[0];
  const float* Sigma = (const float*)d_in[1];
  const float* Q     = (const float*)d_in[2];
  const float* s     = (const float*)d_in[3];
  const float* Theta = (const float*)d_in[4];
  float* out = (float*)d_out;

  // workspace layout: [0,256) scalar acc | [256, 256+128K) t_arr |
  //                   [+2MB) Sigma bf16 | [+64MB) DW bf16   (total ~66.2 MB)
  char* ws = (char*)d_ws;
  float* acc   = (float*)ws;
  float* t_arr = (float*)(ws + 256);
  unsigned short* SigB = (unsigned short*)(ws + 256 + 131072);
  unsigned short* DWb  = (unsigned short*)(ws + 256 + 131072 + 2097152);

  hipMemsetAsync(d_ws, 0, 256 + 131072, stream);  // zero acc + t_arr (ws is poisoned 0xAA)

  prep<<<DOUT, 256, 0, stream>>>((const float4*)W, (const float4*)Q,
                                 (const float4*)Theta, s, (ushort4*)DWb, acc);
  sconv<<<(DIN * DIN) / 1024, 256, 0, stream>>>((const float4*)Sigma, (ushort4*)SigB);
  gemm_fused<<<dim3(8, 256), 256, 0, stream>>>(DWb, SigB, W, t_arr, acc);
  finish<<<1, 1024, 0, stream>>>(t_arr, acc, out);
}

// Round 2
// 507.520 us; speedup vs baseline: 1.5855x; 1.5855x over previous
//
#include <hip/hip_runtime.h>
#include <cstdint>
#include <cstddef>

// Problem: D_OUT=32768, D_IN=1024, all fp32 inputs.
// total = sum(DW*Z) + lamb_reg*sum(1-(2Th-1)^2) + 0.05*4*sum_i (sum_j W*Z)^2
// where DW = W - s*(Q+Th), Z = DW @ Sigma^T  (Z[i,j] = sum_k DW[i,k]*Sigma[j,k])

#define DOUT 32768
#define DIN  1024
#define PREP_BLOCKS 2048
#define PREP_CHUNKS (DOUT / PREP_BLOCKS)   // 16 rows per block

typedef __bf16 bf16x8 __attribute__((ext_vector_type(8)));
typedef float  f32x4  __attribute__((ext_vector_type(4)));

__device__ __forceinline__ unsigned short f2bf(float f) {
  union { float f; unsigned u; } v; v.f = f;
  unsigned u = v.u + 0x7fffu + ((v.u >> 16) & 1u);   // RNE
  return (unsigned short)(u >> 16);
}
__device__ __forceinline__ float bf2f(unsigned short b) {
  union { float f; unsigned u; } v; v.u = ((unsigned)b) << 16;
  return v.f;
}

// ---- Pass 1: DW = W - s*(Q+Th) in bf16; per-block binary-reg partial (NO atomics) ----
// R1 post-mortem: 32768 blocks each atomicAdd'ing ONE address serialized the kernel
// (430us, 628 GB/s, VALUBusy 9%). Now: 2048 blocks x 16 uniform row-chunks, plain
// per-block partial store; finish() reduces bpart[2048].
__global__ __launch_bounds__(256) void prep(
    const float4* __restrict__ W4, const float4* __restrict__ Q4,
    const float4* __restrict__ T4, const float* __restrict__ s,
    ushort4* __restrict__ DW4, float* __restrict__ bpart)
{
  const int tid = threadIdx.x;
  const int b   = blockIdx.x;
  float bsum = 0.f;
#pragma unroll 4
  for (int chunk = 0; chunk < PREP_CHUNKS; ++chunk) {
    const int row = b + chunk * PREP_BLOCKS;       // block-uniform -> s_load for s[row]
    const size_t idx = (size_t)row * 256 + tid;    // 256 float4 per row
    const float sv = s[row];
    const float4 wv = W4[idx];
    const float4 qv = Q4[idx];
    const float4 tv = T4[idx];
    ushort4 dp;
#define COMP(fld) { \
    float th = 0.6f * tanhf(tv.fld) + 0.5f; \
    th = fminf(fmaxf(th, 0.f), 1.f); \
    float um = 2.f * th - 1.f; \
    bsum += 1.f - um * um; \
    dp.fld = f2bf(wv.fld - sv * (qv.fld + th)); }
    COMP(x) COMP(y) COMP(z) COMP(w)
#undef COMP
    DW4[idx] = dp;
  }
  for (int off = 32; off; off >>= 1) bsum += __shfl_down(bsum, off);
  __shared__ float r4[4];
  if ((tid & 63) == 0) r4[tid >> 6] = bsum;
  __syncthreads();
  if (tid == 0) bpart[b] = r4[0] + r4[1] + r4[2] + r4[3];
}

// ---------------- Sigma fp32 -> bf16 ----------------
__global__ __launch_bounds__(256) void sconv(const float4* __restrict__ S4,
                                             ushort4* __restrict__ O4)
{
  const int idx = blockIdx.x * 256 + threadIdx.x;
  float4 v = S4[idx];
  ushort4 o;
  o.x = f2bf(v.x); o.y = f2bf(v.y); o.z = f2bf(v.z); o.w = f2bf(v.w);
  O4[idx] = o;
}

// ---------------- Fused GEMM: Z = DW @ Sigma^T, epilogue reduces ----------------
// 128x128 tile, BK=64, 256 thr (4 waves, 2x2 wave grid, 64x64 each, 4x4 mfma 16x16x32)
__global__ __launch_bounds__(256, 2) void gemm_fused(
    const unsigned short* __restrict__ DW,   // [DOUT][DIN] bf16 bits
    const unsigned short* __restrict__ SG,   // [DIN][DIN]  bf16 bits (Sigma row-major = B^T layout)
    const float* __restrict__ Wf,            // [DOUT][DIN] fp32
    float* __restrict__ t_arr,               // [DOUT]
    float* __restrict__ acc)                 // scalar accumulator
{
  constexpr int K = DIN;
  const int n0 = blockIdx.x * 128;   // 8 n-blocks
  const int m0 = blockIdx.y * 128;   // 256 m-blocks
  const int tid = threadIdx.x;
  const int w = tid >> 6;
  const int lane = tid & 63;
  const int wr = w >> 1, wc = w & 1;

  __shared__ unsigned short As[128 * 64];    // [row][k] 128B pitch
  __shared__ unsigned short Bs[128 * 64];
  __shared__ float red4[4];

  f32x4 accr[4][4];
#pragma unroll
  for (int i = 0; i < 4; ++i)
#pragma unroll
    for (int j = 0; j < 4; ++j) accr[i][j] = (f32x4){0.f, 0.f, 0.f, 0.f};

  const int l8 = lane >> 3;           // sub-row within 1KB chunk
  const int lc = (lane & 7) << 3;     // k-element offset (8 bf16 = 16B)

  for (int kt = 0; kt < K / 64; ++kt) {
    const int k0 = kt * 64;
#pragma unroll
    for (int c = 0; c < 4; ++c) {
      const int sub  = c * 4 + w;               // 0..15 : which 1KB LDS chunk
      const int rowa = sub * 8 + l8;            // 0..127 tile row
      const int ldso = (sub * 64 + lane) * 8;   // element offset (lane*16B within chunk)
      const unsigned short* ga = DW + (size_t)(m0 + rowa) * K + (k0 + lc);
      const unsigned short* gb = SG + (size_t)(n0 + rowa) * K + (k0 + lc);
      __builtin_amdgcn_global_load_lds(
          (const __attribute__((address_space(1))) void*)ga,
          (__attribute__((address_space(3))) void*)(As + ldso), 16, 0, 0);
      __builtin_amdgcn_global_load_lds(
          (const __attribute__((address_space(1))) void*)gb,
          (__attribute__((address_space(3))) void*)(Bs + ldso), 16, 0, 0);
    }
    __syncthreads();

    {
      const int q  = lane >> 4;
      const int mr = lane & 15;
#pragma unroll
      for (int kk = 0; kk < 64; kk += 32) {
        bf16x8 af[4], bfr[4];
        const int kf = kk + q * 8;
#pragma unroll
        for (int ti = 0; ti < 4; ++ti)
          af[ti] = *(const bf16x8*)&As[(wr * 64 + ti * 16 + mr) * 64 + kf];
#pragma unroll
        for (int tj = 0; tj < 4; ++tj)
          bfr[tj] = *(const bf16x8*)&Bs[(wc * 64 + tj * 16 + mr) * 64 + kf];
#pragma unroll
        for (int ti = 0; ti < 4; ++ti)
#pragma unroll
          for (int tj = 0; tj < 4; ++tj)
            accr[ti][tj] = __builtin_amdgcn_mfma_f32_16x16x32_bf16(
                af[ti], bfr[tj], accr[ti][tj], 0, 0, 0);
      }
    }
    __syncthreads();
  }

  // Epilogue: C/D layout col=lane&15, row=(lane>>4)*4+reg
  const int q  = lane >> 4;
  const int cn = lane & 15;
  float actp = 0.f;
#pragma unroll
  for (int ti = 0; ti < 4; ++ti) {
#pragma unroll
    for (int r = 0; r < 4; ++r) {
      const int i = m0 + wr * 64 + ti * 16 + q * 4 + r;
      const float*          wrow  = Wf + (size_t)i * K;
      const unsigned short* dwrow = DW + (size_t)i * K;
      float ts = 0.f;
#pragma unroll
      for (int tj = 0; tj < 4; ++tj) {
        const int j = n0 + wc * 64 + tj * 16 + cn;
        const float z = accr[ti][tj][r];
        ts   = fmaf(wrow[j], z, ts);          // t_i partial
        actp = fmaf(bf2f(dwrow[j]), z, actp); // activation partial
      }
#pragma unroll
      for (int off = 8; off; off >>= 1) ts += __shfl_xor(ts, off, 16);
      if (cn == 0) atomicAdd(&t_arr[i], ts);
    }
  }
  for (int off = 32; off; off >>= 1) actp += __shfl_down(actp, off);
  if (lane == 0) red4[w] = actp;
  __syncthreads();
  if (tid == 0) atomicAdd(acc, red4[0] + red4[1] + red4[2] + red4[3]);
}

// ---------------- Final: out = acc + 0.2*sum(t_i^2) + 2e-4*sum(bpart) ----------------
__global__ __launch_bounds__(1024) void finish(const float* __restrict__ t_arr,
                                               const float* __restrict__ bpart,
                                               const float* __restrict__ acc,
                                               float* __restrict__ out)
{
  __shared__ float red[16];
  float g = 0.f;
  for (int i = threadIdx.x; i < DOUT; i += 1024) {
    float t = t_arr[i];
    g = fmaf(0.2f * t, t, g);                 // lamb*4 = 0.05*4 = 0.2
  }
  for (int i = threadIdx.x; i < PREP_BLOCKS; i += 1024)
    g = fmaf(2.0e-4f, bpart[i], g);
  for (int off = 32; off; off >>= 1) g += __shfl_down(g, off);
  if ((threadIdx.x & 63) == 0) red[threadIdx.x >> 6] = g;
  __syncthreads();
  if (threadIdx.x == 0) {
    float tot = 0.f;
#pragma unroll
    for (int i = 0; i < 16; ++i) tot += red[i];
    out[0] = acc[0] + tot;
  }
}

extern "C" void kernel_launch(void* const* d_in, const int* in_sizes, int n_in,
                              void* d_out, int out_size, void* d_ws, size_t ws_size,
                              hipStream_t stream) {
  const float* W     = (const float*)d_in[0];
  const float* Sigma = (const float*)d_in[1];
  const float* Q     = (const float*)d_in[2];
  const float* s     = (const float*)d_in[3];
  const float* Theta = (const float*)d_in[4];
  float* out = (float*)d_out;

  // ws layout: [0,256) acc | [256,+128K) t_arr | [+8K) bpart | [+2MB) Sigma bf16 | [+64MB) DW bf16
  char* ws = (char*)d_ws;
  float* acc   = (float*)ws;
  float* t_arr = (float*)(ws + 256);
  float* bpart = (float*)(ws + 256 + 131072);
  unsigned short* SigB = (unsigned short*)(ws + 256 + 131072 + 8192);
  unsigned short* DWb  = (unsigned short*)(ws + 256 + 131072 + 8192 + 2097152);

  hipMemsetAsync(d_ws, 0, 256 + 131072, stream);  // zero acc + t_arr (ws poisoned 0xAA)

  prep<<<PREP_BLOCKS, 256, 0, stream>>>((const float4*)W, (const float4*)Q,
                                        (const float4*)Theta, s, (ushort4*)DWb, bpart);
  sconv<<<(DIN * DIN) / 1024, 256, 0, stream>>>((const float4*)Sigma, (ushort4*)SigB);
  gemm_fused<<<dim3(8, 256), 256, 0, stream>>>(DWb, SigB, W, t_arr, acc);
  finish<<<1, 1024, 0, stream>>>(t_arr, bpart, acc, out);
}

// Round 3
// 501.067 us; speedup vs baseline: 1.6059x; 1.0129x over previous
//
#include <hip/hip_runtime.h>
#include <cstdint>
#include <cstddef>

// Problem: D_OUT=32768, D_IN=1024, all fp32 inputs.
// total = sum(DW*Z) + lamb_reg*sum(1-(2Th-1)^2) + 0.05*4*sum_i (sum_j W*Z)^2
// where DW = W - s*(Q+Th), Z = DW @ Sigma^T  (Z[i,j] = sum_k DW[i,k]*Sigma[j,k])

#define DOUT 32768
#define DIN  1024
#define PREP_BLOCKS 2048
#define PREP_CHUNKS (DOUT / PREP_BLOCKS)   // 16 rows per block

typedef __bf16 bf16x8 __attribute__((ext_vector_type(8)));
typedef float  f32x4  __attribute__((ext_vector_type(4)));

__device__ __forceinline__ unsigned short f2bf(float f) {
  union { float f; unsigned u; } v; v.f = f;
  unsigned u = v.u + 0x7fffu + ((v.u >> 16) & 1u);   // RNE
  return (unsigned short)(u >> 16);
}
__device__ __forceinline__ float bf2f(unsigned short b) {
  union { float f; unsigned u; } v; v.u = ((unsigned)b) << 16;
  return v.f;
}

// ---- Pass 1: DW = W - s*(Q+Th) in bf16; per-block binary-reg partial ----
// R2: tanhf (libm: branchy + real divide) throttled issue slots at VALUBusy 23%,
// 2 TB/s. Closed form: th = clamp(1.1 - 1.2/(e^{2x}+1), 0, 1) via v_exp+v_rcp.
__global__ __launch_bounds__(256) void prep(
    const float4* __restrict__ W4, const float4* __restrict__ Q4,
    const float4* __restrict__ T4, const float* __restrict__ s,
    ushort4* __restrict__ DW4, float* __restrict__ bpart)
{
  const int tid = threadIdx.x;
  const int b   = blockIdx.x;
  float bsum = 0.f;
#pragma unroll 8
  for (int chunk = 0; chunk < PREP_CHUNKS; ++chunk) {
    const int row = b + chunk * PREP_BLOCKS;       // block-uniform -> s_load for s[row]
    const size_t idx = (size_t)row * 256 + tid;    // 256 float4 per row
    const float sv = s[row];
    const float4 wv = W4[idx];
    const float4 qv = Q4[idx];
    const float4 tv = T4[idx];
    ushort4 dp;
#define COMP(fld) { \
    float e  = __builtin_amdgcn_exp2f(tv.fld * 2.885390082f); /* e^(2x) */ \
    float th = 1.1f - 1.2f * __builtin_amdgcn_rcpf(e + 1.f); \
    th = fminf(fmaxf(th, 0.f), 1.f); \
    float um = 2.f * th - 1.f; \
    bsum += 1.f - um * um; \
    dp.fld = f2bf(wv.fld - sv * (qv.fld + th)); }
    COMP(x) COMP(y) COMP(z) COMP(w)
#undef COMP
    DW4[idx] = dp;
  }
  for (int off = 32; off; off >>= 1) bsum += __shfl_down(bsum, off);
  __shared__ float r4[4];
  if ((tid & 63) == 0) r4[tid >> 6] = bsum;
  __syncthreads();
  if (tid == 0) bpart[b] = r4[0] + r4[1] + r4[2] + r4[3];
}

// ---------------- Sigma fp32 -> bf16 ----------------
__global__ __launch_bounds__(256) void sconv(const float4* __restrict__ S4,
                                             ushort4* __restrict__ O4)
{
  const int idx = blockIdx.x * 256 + threadIdx.x;
  float4 v = S4[idx];
  ushort4 o;
  o.x = f2bf(v.x); o.y = f2bf(v.y); o.z = f2bf(v.z); o.w = f2bf(v.w);
  O4[idx] = o;
}

// ---------------- Fused GEMM: Z = DW @ Sigma^T, epilogue reduces ----------------
// 128x128 tile, BK=64, 256 thr (4 waves, 2x2 wave grid, 64x64 each, 4x4 mfma 16x16x32)
// R2 fixes: (a) XOR swizzle: logical k-chunk c of row r lives at physical chunk
// c^(r&7); applied on the GLOBAL-read side since global_load_lds dst is
// lane-contiguous. Kills the 16-way read conflicts (2.5e7 cycles).
// (b) 1-D grid + XCD swizzle: the 8 n-blocks sharing a DW m-tile land on ONE
// XCD consecutively -> tile read once into its L2 instead of 8 HBM fetches.
__global__ __launch_bounds__(256, 4) void gemm_fused(
    const unsigned short* __restrict__ DW,   // [DOUT][DIN] bf16 bits
    const unsigned short* __restrict__ SG,   // [DIN][DIN]  bf16 bits (Sigma row-major = B^T layout)
    const float* __restrict__ Wf,            // [DOUT][DIN] fp32
    float* __restrict__ t_arr,               // [DOUT]
    float* __restrict__ acc)                 // scalar accumulator
{
  constexpr int K = DIN;
  const int lb  = blockIdx.x;                // 2048 blocks
  const int xcd = lb & 7;
  const int idx = lb >> 3;                   // 0..255
  const int m0  = (xcd * 32 + (idx >> 3)) * 128;
  const int n0  = (idx & 7) * 128;
  const int tid = threadIdx.x;
  const int w = tid >> 6;
  const int lane = tid & 63;
  const int wr = w >> 1, wc = w & 1;

  __shared__ unsigned short As[128 * 64];    // [row][k-chunk swizzled] 128B pitch
  __shared__ unsigned short Bs[128 * 64];
  __shared__ float red4[4];

  f32x4 accr[4][4];
#pragma unroll
  for (int i = 0; i < 4; ++i)
#pragma unroll
    for (int j = 0; j < 4; ++j) accr[i][j] = (f32x4){0.f, 0.f, 0.f, 0.f};

  const int l8 = lane >> 3;                     // sub-row within 1KB chunk (0..7)
  const int lc = ((lane & 7) ^ l8) << 3;        // swizzled k-element offset (8 bf16 = 16B)

  for (int kt = 0; kt < K / 64; ++kt) {
    const int k0 = kt * 64;
#pragma unroll
    for (int c = 0; c < 4; ++c) {
      const int sub  = c * 4 + w;               // 0..15 : which 1KB LDS chunk
      const int rowa = sub * 8 + l8;            // 0..127 tile row
      const int ldso = (sub * 64 + lane) * 8;   // element offset (lane*16B within chunk)
      const unsigned short* ga = DW + (size_t)(m0 + rowa) * K + (k0 + lc);
      const unsigned short* gb = SG + (size_t)(n0 + rowa) * K + (k0 + lc);
      __builtin_amdgcn_global_load_lds(
          (const __attribute__((address_space(1))) void*)ga,
          (__attribute__((address_space(3))) void*)(As + ldso), 16, 0, 0);
      __builtin_amdgcn_global_load_lds(
          (const __attribute__((address_space(1))) void*)gb,
          (__attribute__((address_space(3))) void*)(Bs + ldso), 16, 0, 0);
    }
    __syncthreads();

    {
      const int q   = lane >> 4;
      const int mr  = lane & 15;
      const int mr7 = mr & 7;
#pragma unroll
      for (int kk = 0; kk < 64; kk += 32) {
        bf16x8 af[4], bfr[4];
        const int cl  = (kk >> 3) + q;          // logical chunk (0..7)
        const int pc8 = ((cl ^ mr7) << 3);      // physical chunk offset, elements
#pragma unroll
        for (int ti = 0; ti < 4; ++ti)
          af[ti] = *(const bf16x8*)&As[(wr * 64 + ti * 16 + mr) * 64 + pc8];
#pragma unroll
        for (int tj = 0; tj < 4; ++tj)
          bfr[tj] = *(const bf16x8*)&Bs[(wc * 64 + tj * 16 + mr) * 64 + pc8];
#pragma unroll
        for (int ti = 0; ti < 4; ++ti)
#pragma unroll
          for (int tj = 0; tj < 4; ++tj)
            accr[ti][tj] = __builtin_amdgcn_mfma_f32_16x16x32_bf16(
                af[ti], bfr[tj], accr[ti][tj], 0, 0, 0);
      }
    }
    __syncthreads();
  }

  // Epilogue: C/D layout col=lane&15, row=(lane>>4)*4+reg
  const int q  = lane >> 4;
  const int cn = lane & 15;
  float actp = 0.f;
#pragma unroll
  for (int ti = 0; ti < 4; ++ti) {
#pragma unroll
    for (int r = 0; r < 4; ++r) {
      const int i = m0 + wr * 64 + ti * 16 + q * 4 + r;
      const float*          wrow  = Wf + (size_t)i * K;
      const unsigned short* dwrow = DW + (size_t)i * K;
      float ts = 0.f;
#pragma unroll
      for (int tj = 0; tj < 4; ++tj) {
        const int j = n0 + wc * 64 + tj * 16 + cn;
        const float z = accr[ti][tj][r];
        ts   = fmaf(wrow[j], z, ts);          // t_i partial
        actp = fmaf(bf2f(dwrow[j]), z, actp); // activation partial
      }
#pragma unroll
      for (int off = 8; off; off >>= 1) ts += __shfl_xor(ts, off, 16);
      if (cn == 0) atomicAdd(&t_arr[i], ts);
    }
  }
  for (int off = 32; off; off >>= 1) actp += __shfl_down(actp, off);
  if (lane == 0) red4[w] = actp;
  __syncthreads();
  if (tid == 0) atomicAdd(acc, red4[0] + red4[1] + red4[2] + red4[3]);
}

// ---------------- Final: out = acc + 0.2*sum(t_i^2) + 2e-4*sum(bpart) ----------------
__global__ __launch_bounds__(1024) void finish(const float* __restrict__ t_arr,
                                               const float* __restrict__ bpart,
                                               const float* __restrict__ acc,
                                               float* __restrict__ out)
{
  __shared__ float red[16];
  float g = 0.f;
  for (int i = threadIdx.x; i < DOUT; i += 1024) {
    float t = t_arr[i];
    g = fmaf(0.2f * t, t, g);                 // lamb*4 = 0.05*4 = 0.2
  }
  for (int i = threadIdx.x; i < PREP_BLOCKS; i += 1024)
    g = fmaf(2.0e-4f, bpart[i], g);
  for (int off = 32; off; off >>= 1) g += __shfl_down(g, off);
  if ((threadIdx.x & 63) == 0) red[threadIdx.x >> 6] = g;
  __syncthreads();
  if (threadIdx.x == 0) {
    float tot = 0.f;
#pragma unroll
    for (int i = 0; i < 16; ++i) tot += red[i];
    out[0] = acc[0] + tot;
  }
}

extern "C" void kernel_launch(void* const* d_in, const int* in_sizes, int n_in,
                              void* d_out, int out_size, void* d_ws, size_t ws_size,
                              hipStream_t stream) {
  const float* W     = (const float*)d_in[0];
  const float* Sigma = (const float*)d_in[1];
  const float* Q     = (const float*)d_in[2];
  const float* s     = (const float*)d_in[3];
  const float* Theta = (const float*)d_in[4];
  float* out = (float*)d_out;

  // ws layout: [0,256) acc | [256,+128K) t_arr | [+8K) bpart | [+2MB) Sigma bf16 | [+64MB) DW bf16
  char* ws = (char*)d_ws;
  float* acc   = (float*)ws;
  float* t_arr = (float*)(ws + 256);
  float* bpart = (float*)(ws + 256 + 131072);
  unsigned short* SigB = (unsigned short*)(ws + 256 + 131072 + 8192);
  unsigned short* DWb  = (unsigned short*)(ws + 256 + 131072 + 8192 + 2097152);

  hipMemsetAsync(d_ws, 0, 256 + 131072, stream);  // zero acc + t_arr (ws poisoned 0xAA)

  prep<<<PREP_BLOCKS, 256, 0, stream>>>((const float4*)W, (const float4*)Q,
                                        (const float4*)Theta, s, (ushort4*)DWb, bpart);
  sconv<<<(DIN * DIN) / 1024, 256, 0, stream>>>((const float4*)Sigma, (ushort4*)SigB);
  gemm_fused<<<2048, 256, 0, stream>>>(DWb, SigB, W, t_arr, acc);
  finish<<<1, 1024, 0, stream>>>(t_arr, bpart, acc, out);
}